// Round 11
// baseline (8947.520 us; speedup 1.0000x reference)
//
#include <hip/hip_runtime.h>
#include <hip/hip_bf16.h>
#include <stdint.h>

typedef unsigned short u16;
typedef short s16x8 __attribute__((ext_vector_type(8)));
typedef float f32x4 __attribute__((ext_vector_type(4)));

#define D_ 256
#define H_ 8
#define L_ 6
#define F_ 1024
#define MAXB_ 50
#define S_ 53
#define B_ 4096

__device__ __forceinline__ u16 f2b(float f){
  __hip_bfloat16 h = __float2bfloat16(f);   // RNE
  return *reinterpret_cast<u16*>(&h);
}
__device__ __forceinline__ float b2f(u16 u){
  __hip_bfloat16 h = *reinterpret_cast<__hip_bfloat16*>(&u);
  return __bfloat162float(h);
}

__device__ __forceinline__ void gload16(const void* g, void* l){
  __builtin_amdgcn_global_load_lds((__attribute__((address_space(1))) void*)(g),
                                   (__attribute__((address_space(3))) void*)(l), 16, 0, 0);
}

// ---------------------------------------------------------------- weights prep
__global__ __launch_bounds__(256) void prep_weights(
    const float* __restrict__ qkvW, const float* __restrict__ outW,
    const float* __restrict__ w1,   const float* __restrict__ w2,
    u16* __restrict__ qkvT, u16* __restrict__ outT,
    u16* __restrict__ w1T,  u16* __restrict__ w2T)
{
  const int i = blockIdx.x * 256 + threadIdx.x;
  if (i < L_*768*256) {            // qkvT[l][n<768][k<256]
    const int l = i / (768*256); const int r = i % (768*256);
    const int n = r >> 8; const int k = r & 255;
    qkvT[i] = f2b(qkvW[((size_t)l*256 + k)*768 + n]);
  }
  if (i < L_*256*256) {            // outT[l][n<256][k<256]
    const int l = i >> 16; const int r = i & 65535;
    const int n = r >> 8; const int k = r & 255;
    outT[i] = f2b(outW[((size_t)l*256 + k)*256 + n]);
  }
  if (i < L_*1024*256) {           // w1T[l][n<1024][k<256]
    const int l = i / (1024*256); const int r = i % (1024*256);
    const int n = r >> 8; const int k = r & 255;
    w1T[i] = f2b(w1[((size_t)l*256 + k)*1024 + n]);
  }
  if (i < L_*256*1024) {           // w2T[l][n<256][k<1024]
    const int l = i / (256*1024); const int r = i % (256*1024);
    const int n = r >> 10; const int k = r & 1023;
    w2T[i] = f2b(w2[((size_t)l*1024 + k)*256 + n]);
  }
}

// ---------------------------------------------------------------- embedding (per chunk)
__global__ __launch_bounds__(256) void embed_kernel(
    const float* __restrict__ obs,
    const float* __restrict__ cls_emb, const float* __restrict__ type_cls,
    const float* __restrict__ type_ctx, const float* __restrict__ type_pred,
    const float* __restrict__ type_boid,
    const float* __restrict__ ctxW, const float* __restrict__ ctxb,
    const float* __restrict__ predW, const float* __restrict__ predb,
    const float* __restrict__ boidW, const float* __restrict__ boidb,
    u16* __restrict__ xbf, int* __restrict__ nvalid)
{
  const int b = blockIdx.x, tid = threadIdx.x;
  __shared__ float obs_s[204];
  __shared__ int perm_s[MAXB_];
  __shared__ int count_s;
  const float* orow = obs + (size_t)b * 204;
  if (tid < 204) obs_s[tid] = orow[tid];
  __syncthreads();
  if (tid < 64) {
    const int j = tid;
    bool flag = false;
    if (j < MAXB_) {
      const float a0=obs_s[4+4*j], a1=obs_s[5+4*j], a2=obs_s[6+4*j], a3=obs_s[7+4*j];
      flag = (a0!=0.f)||(a1!=0.f)||(a2!=0.f)||(a3!=0.f);
    }
    const unsigned long long m = __ballot(flag);
    if (flag) perm_s[__popcll(m & ((1ull<<j)-1ull))] = j;
    if (j == 0) { count_s = __popcll(m); nvalid[b] = __popcll(m); }
  }
  __syncthreads();
  const int cnt = count_s;
  const int d = tid;
  for (int s = 0; s < S_; ++s) {
    float v;
    if (s == 0)      v = cls_emb[d] + type_cls[d];
    else if (s == 1) v = obs_s[0]*ctxW[d] + obs_s[1]*ctxW[256+d] + ctxb[d] + type_ctx[d];
    else if (s == 2) v = obs_s[2]*predW[d] + obs_s[3]*predW[256+d] + predb[d] + type_pred[d];
    else {
      const int j = s - 3;
      if (j < cnt) {
        const int bj = perm_s[j];
        v = obs_s[4+4*bj]*boidW[d] + obs_s[5+4*bj]*boidW[256+d]
          + obs_s[6+4*bj]*boidW[512+d] + obs_s[7+4*bj]*boidW[768+d]
          + boidb[d] + type_boid[d];
      } else v = 0.f;
    }
    xbf[((size_t)b*S_ + s)*256 + d] = f2b(v);
  }
}

// ---------------------------------------------------------------- GEMM + bias (QKV)
// R5-proven: 128x128 tile, BK=64, 4 waves, dbuf prefetch-before-compute, T2 swizzle.
template<bool RELU>
__global__ __launch_bounds__(256, 2) void gemm_bias_kernel(
    const u16* __restrict__ A, const u16* __restrict__ Bt,
    const float* __restrict__ bias, u16* __restrict__ C,
    int N, int K)
{
  __shared__ __attribute__((aligned(16))) u16 As[2][128*64];
  __shared__ __attribute__((aligned(16))) u16 Bs[2][128*64];
  const int tid = threadIdx.x;
  const int w = tid >> 6, lane = tid & 63;
  const int wr = w >> 1, wc = w & 1;
  const int lm = lane & 15, lg = lane >> 4;
  const int lrow = lane >> 3;
  const int lxor = ((lane & 7) ^ lrow) * 8;
  const int m0 = blockIdx.x * 128, n0 = blockIdx.y * 128;
  const int cb0 = (lg*16) ^ ((lm & 7) << 4);
  const int cb1 = (64 + lg*16) ^ ((lm & 7) << 4);

  f32x4 acc[4][4];
  #pragma unroll
  for (int m=0;m<4;m++)
    #pragma unroll
    for (int n=0;n<4;n++)
      #pragma unroll
      for (int t=0;t<4;t++) acc[m][n][t] = 0.f;

  #pragma unroll
  for (int j=0;j<4;j++){
    const int chunk = w*4 + j;
    const int row = chunk*8 + lrow;
    gload16(A  + (size_t)(m0+row)*K + lxor, &As[0][chunk*512]);
    gload16(Bt + (size_t)(n0+row)*K + lxor, &Bs[0][chunk*512]);
  }
  __syncthreads();

  const int NT = K >> 6;
  for (int t = 0; t < NT; ++t) {
    const int cur = t & 1;
    if (t + 1 < NT) {
      const int k0 = (t+1) << 6;
      #pragma unroll
      for (int j=0;j<4;j++){
        const int chunk = w*4 + j;
        const int row = chunk*8 + lrow;
        gload16(A  + (size_t)(m0+row)*K + k0 + lxor, &As[cur^1][chunk*512]);
        gload16(Bt + (size_t)(n0+row)*K + k0 + lxor, &Bs[cur^1][chunk*512]);
      }
    }
    const char* Ab = (const char*)As[cur];
    const char* Bb = (const char*)Bs[cur];
    #pragma unroll
    for (int kk=0;kk<2;kk++){
      const int cb = kk ? cb1 : cb0;
      s16x8 af[4], bfr[4];
      #pragma unroll
      for (int m=0;m<4;m++) af[m]  = *reinterpret_cast<const s16x8*>(Ab + (wr*64 + m*16 + lm)*128 + cb);
      #pragma unroll
      for (int n=0;n<4;n++) bfr[n] = *reinterpret_cast<const s16x8*>(Bb + (wc*64 + n*16 + lm)*128 + cb);
      #pragma unroll
      for (int m=0;m<4;m++)
        #pragma unroll
        for (int n=0;n<4;n++)
          acc[m][n] = __builtin_amdgcn_mfma_f32_16x16x32_bf16(af[m], bfr[n], acc[m][n], 0, 0, 0);
    }
    __syncthreads();
  }

  #pragma unroll
  for (int n=0;n<4;n++){
    const int col = n0 + wc*64 + n*16 + lm;
    const float bv = bias[col];
    #pragma unroll
    for (int m=0;m<4;m++){
      const int r0 = m0 + wr*64 + m*16 + lg*4;
      #pragma unroll
      for (int j=0;j<4;j++){
        float v = acc[m][n][j] + bv;
        if (RELU) v = fmaxf(v, 0.f);
        C[(size_t)(r0+j)*N + col] = f2b(v);
      }
    }
  }
}

// ---------------------------------------------------------------- attention
__global__ __launch_bounds__(64) void attn_kernel(
    const u16* __restrict__ qkv, u16* __restrict__ O, const int* __restrict__ nvalid)
{
  const int bh = blockIdx.x;
  const int b = bh >> 3, h = bh & 7;
  const int lane = threadIdx.x;
  const int lm = lane & 15, lg = lane >> 4;
  __shared__ __attribute__((aligned(16))) u16 Pl[64*72];
  __shared__ __attribute__((aligned(16))) u16 VT[32*72];
  const size_t base = (size_t)b * S_ * 768;

  s16x8 aQ[4], aK[4];
  #pragma unroll
  for (int t=0;t<4;t++){
    const int r = t*16 + lm;
    if (r < S_){
      aQ[t] = *reinterpret_cast<const s16x8*>(&qkv[base + (size_t)r*768 +       h*32 + lg*8]);
      aK[t] = *reinterpret_cast<const s16x8*>(&qkv[base + (size_t)r*768 + 256 + h*32 + lg*8]);
    } else {
      #pragma unroll
      for (int i=0;i<8;i++){ aQ[t][i]=0; aK[t][i]=0; }
    }
  }
  {
    const int s = lane;
    #pragma unroll
    for (int i4=0;i4<4;i4++){
      s16x8 v;
      if (s < S_) v = *reinterpret_cast<const s16x8*>(&qkv[base + (size_t)s*768 + 512 + h*32 + i4*8]);
      else {
        #pragma unroll
        for (int i=0;i<8;i++) v[i]=0;
      }
      #pragma unroll
      for (int t=0;t<8;t++) VT[(i4*8+t)*72 + s] = (u16)v[t];
    }
  }
  f32x4 zf;
  #pragma unroll
  for (int t=0;t<4;t++) zf[t] = 0.f;
  f32x4 sc[4][4];
  #pragma unroll
  for (int qi=0;qi<4;qi++)
    #pragma unroll
    for (int kj=0;kj<4;kj++)
      sc[qi][kj] = __builtin_amdgcn_mfma_f32_16x16x32_bf16(aQ[qi], aK[kj], zf, 0, 0, 0);

  const int T = 3 + nvalid[b];
  const float scale = 0.17677669529663689f;
  __syncthreads();

  #pragma unroll
  for (int qi=0;qi<4;qi++){
    #pragma unroll
    for (int j=0;j<4;j++){
      float v[4];
      #pragma unroll
      for (int kj=0;kj<4;kj++)
        v[kj] = sc[qi][kj][j]*scale + ((kj*16+lm) < T ? 0.f : -1e9f);
      float mx = fmaxf(fmaxf(v[0],v[1]), fmaxf(v[2],v[3]));
      mx = fmaxf(mx, __shfl_xor(mx, 1));
      mx = fmaxf(mx, __shfl_xor(mx, 2));
      mx = fmaxf(mx, __shfl_xor(mx, 4));
      mx = fmaxf(mx, __shfl_xor(mx, 8));
      float e[4]; float sum = 0.f;
      #pragma unroll
      for (int kj=0;kj<4;kj++){ e[kj] = __expf(v[kj]-mx); sum += e[kj]; }
      sum += __shfl_xor(sum, 1);
      sum += __shfl_xor(sum, 2);
      sum += __shfl_xor(sum, 4);
      sum += __shfl_xor(sum, 8);
      const float inv = 1.f / sum;
      const int q = qi*16 + lg*4 + j;
      #pragma unroll
      for (int kj=0;kj<4;kj++) Pl[q*72 + kj*16 + lm] = f2b(e[kj]*inv);
    }
  }
  __syncthreads();

  s16x8 bV[2][2];
  #pragma unroll
  for (int c=0;c<2;c++)
    #pragma unroll
    for (int dj=0;dj<2;dj++)
      bV[c][dj] = *reinterpret_cast<const s16x8*>(&VT[(dj*16+lm)*72 + c*32 + lg*8]);

  f32x4 oa[4][2];
  #pragma unroll
  for (int qi=0;qi<4;qi++)
    #pragma unroll
    for (int dj=0;dj<2;dj++)
      #pragma unroll
      for (int t=0;t<4;t++) oa[qi][dj][t] = 0.f;

  #pragma unroll
  for (int qi=0;qi<4;qi++){
    #pragma unroll
    for (int c=0;c<2;c++){
      const s16x8 aP = *reinterpret_cast<const s16x8*>(&Pl[(qi*16+lm)*72 + c*32 + lg*8]);
      #pragma unroll
      for (int dj=0;dj<2;dj++)
        oa[qi][dj] = __builtin_amdgcn_mfma_f32_16x16x32_bf16(aP, bV[c][dj], oa[qi][dj], 0, 0, 0);
    }
  }
  #pragma unroll
  for (int qi=0;qi<4;qi++)
    #pragma unroll
    for (int dj=0;dj<2;dj++)
      #pragma unroll
      for (int j=0;j<4;j++){
        const int q = qi*16 + lg*4 + j;
        if (q < S_)
          O[((size_t)(b*S_ + q))*256 + h*32 + dj*16 + lm] = f2b(oa[qi][dj][j]);
      }
}

// ---------------------------------------------------------------- GEMM + bias + residual + LN (out-proj, K=256)
// R3/R6-verified: 64 rows x 256 cols; 4 waves; single-buffer; T2 swizzle.
__global__ __launch_bounds__(256, 2) void gemm_ln_kernel(
    const u16* __restrict__ A, const u16* __restrict__ Bt,
    const float* __restrict__ bias, const float* __restrict__ lng, const float* __restrict__ lnb,
    u16* __restrict__ xbf, int K)
{
  __shared__ __attribute__((aligned(16))) u16 As[64*64];
  __shared__ __attribute__((aligned(16))) u16 Bs[256*64];
  __shared__ float redS[4][64];
  __shared__ float redQ[4][64];
  const int tid = threadIdx.x;
  const int w = tid >> 6, lane = tid & 63;
  const int lm = lane & 15, lg = lane >> 4;
  const int lrow = lane >> 3;
  const int lxor = ((lane & 7) ^ lrow) * 8;
  const int m0 = blockIdx.x * 64;
  const int cb0 = ((lg*16) ^ ((lm & 7) << 4));
  const int cb1 = ((64 + lg*16) ^ ((lm & 7) << 4));

  f32x4 acc[4][4];
  #pragma unroll
  for (int m=0;m<4;m++)
    #pragma unroll
    for (int n=0;n<4;n++)
      #pragma unroll
      for (int t=0;t<4;t++) acc[m][n][t] = 0.f;

  const char* Ab = (const char*)As;
  const char* Bb = (const char*)Bs;

  for (int k0 = 0; k0 < K; k0 += 64) {
    #pragma unroll
    for (int j=0;j<2;j++){
      const int chunk = w*2 + j;
      gload16(A + (size_t)(m0 + chunk*8 + lrow)*K + k0 + lxor, &As[chunk*512]);
    }
    #pragma unroll
    for (int j=0;j<8;j++){
      const int chunk = w*8 + j;
      gload16(Bt + (size_t)(chunk*8 + lrow)*K + k0 + lxor, &Bs[chunk*512]);
    }
    __syncthreads();
    #pragma unroll
    for (int kk=0;kk<2;kk++){
      const int cb = kk ? cb1 : cb0;
      s16x8 af[4], bfr[4];
      #pragma unroll
      for (int m=0;m<4;m++) af[m]  = *reinterpret_cast<const s16x8*>(Ab + (m*16 + lm)*128 + cb);
      #pragma unroll
      for (int n=0;n<4;n++) bfr[n] = *reinterpret_cast<const s16x8*>(Bb + (w*64 + n*16 + lm)*128 + cb);
      #pragma unroll
      for (int m=0;m<4;m++)
        #pragma unroll
        for (int n=0;n<4;n++)
          acc[m][n] = __builtin_amdgcn_mfma_f32_16x16x32_bf16(af[m], bfr[n], acc[m][n], 0, 0, 0);
    }
    __syncthreads();
  }

  float bb[4];
  #pragma unroll
  for (int n=0;n<4;n++) bb[n] = bias[w*64 + n*16 + lm];
  #pragma unroll
  for (int m=0;m<4;m++)
    #pragma unroll
    for (int j=0;j<4;j++){
      const int r = m*16 + lg*4 + j;
      const u16* resp = xbf + (size_t)(m0+r)*256 + w*64 + lm;
      #pragma unroll
      for (int n=0;n<4;n++) acc[m][n][j] += bb[n] + b2f(resp[n*16]);
    }

  #pragma unroll
  for (int m=0;m<4;m++)
    #pragma unroll
    for (int j=0;j<4;j++){
      float s1 = 0.f, s2 = 0.f;
      #pragma unroll
      for (int n=0;n<4;n++){ const float t2 = acc[m][n][j]; s1 += t2; s2 += t2*t2; }
      s1 += __shfl_xor(s1, 1); s2 += __shfl_xor(s2, 1);
      s1 += __shfl_xor(s1, 2); s2 += __shfl_xor(s2, 2);
      s1 += __shfl_xor(s1, 4); s2 += __shfl_xor(s2, 4);
      s1 += __shfl_xor(s1, 8); s2 += __shfl_xor(s2, 8);
      if (lm == 0){ const int r = m*16 + lg*4 + j; redS[w][r] = s1; redQ[w][r] = s2; }
    }
  __syncthreads();

  float gg[4], be[4];
  #pragma unroll
  for (int n=0;n<4;n++){ const int col = w*64 + n*16 + lm; gg[n] = lng[col]; be[n] = lnb[col]; }
  #pragma unroll
  for (int m=0;m<4;m++)
    #pragma unroll
    for (int j=0;j<4;j++){
      const int r = m*16 + lg*4 + j;
      const float sum = redS[0][r]+redS[1][r]+redS[2][r]+redS[3][r];
      const float sq  = redQ[0][r]+redQ[1][r]+redQ[2][r]+redQ[3][r];
      const float mean = sum * (1.f/256.f);
      const float var  = sq  * (1.f/256.f) - mean*mean;
      const float rstd = rsqrtf(var + 1e-5f);
      #pragma unroll
      for (int n=0;n<4;n++){
        const float y = (acc[m][n][j] - mean)*rstd*gg[n] + be[n];
        xbf[(size_t)(m0+r)*256 + w*64 + n*16 + lm] = f2b(y);
      }
    }
}

// ---------------------------------------------------------------- FUSED FFN v2: x = LN(x + relu(x@W1+b1)@W2 + b2)
// 32-row tiles, 512 thr (8 waves), h[32][1024] in 64 KB LDS -> 2 blocks/CU (the
// R9 version's 132 KB forced 1 blk/CU = 2 waves/SIMD; that was the regression).
__global__ __launch_bounds__(512, 2) void ffn2_kernel(
    const u16* __restrict__ xbf,
    const u16* __restrict__ w1t,  const float* __restrict__ b1,
    const u16* __restrict__ w2t,  const float* __restrict__ b2,
    const float* __restrict__ lng, const float* __restrict__ lnb)
{
  __shared__ __attribute__((aligned(16))) u16 hls[32*1024];  // 64 KB
  __shared__ float redS[8][32];
  __shared__ float redQ[8][32];
  const int tid = threadIdx.x;
  const int w = tid >> 6, lane = tid & 63;
  const int lm = lane & 15, lg = lane >> 4;
  const int m0 = blockIdx.x * 32;

  // ---------------- phase 1: h[0:32][w*128 : w*128+128] = relu(x@W1 + b1)
  {
    const int n0 = w*128;
    f32x4 acc[2][8];
    #pragma unroll
    for (int m=0;m<2;m++)
      #pragma unroll
      for (int n=0;n<8;n++)
        #pragma unroll
        for (int t=0;t<4;t++) acc[m][n][t] = 0.f;
    #pragma unroll
    for (int kf=0; kf<8; ++kf) {
      s16x8 af[2], bfr[8];
      #pragma unroll
      for (int m=0;m<2;m++)
        af[m] = *reinterpret_cast<const s16x8*>(&xbf[(size_t)(m0+m*16+lm)*256 + kf*32 + lg*8]);
      #pragma unroll
      for (int n=0;n<8;n++)
        bfr[n] = *reinterpret_cast<const s16x8*>(&w1t[(size_t)(n0+n*16+lm)*256 + kf*32 + lg*8]);
      #pragma unroll
      for (int m=0;m<2;m++)
        #pragma unroll
        for (int n=0;n<8;n++)
          acc[m][n] = __builtin_amdgcn_mfma_f32_16x16x32_bf16(af[m], bfr[n], acc[m][n], 0, 0, 0);
    }
    float bb1[8];
    #pragma unroll
    for (int n=0;n<8;n++) bb1[n] = b1[n0 + n*16 + lm];
    // swizzled store: elem (r,c) -> hls[r*1024 + (c ^ ((r&7)<<3))]
    #pragma unroll
    for (int m=0;m<2;m++)
      #pragma unroll
      for (int j=0;j<4;j++){
        const int r = m*16 + lg*4 + j;
        const int sw = (r & 7) << 3;
        #pragma unroll
        for (int n=0;n<8;n++){
          const int c = n0 + n*16 + lm;
          hls[r*1024 + (c ^ sw)] = f2b(fmaxf(acc[m][n][j] + bb1[n], 0.f));
        }
      }
  }
  __syncthreads();

  // ---------------- phase 2: y[0:32][w*32 : w*32+32] = h @ W2 + b2, K=1024
  const int nc0 = w*32;
  f32x4 a2[2][2];
  #pragma unroll
  for (int m=0;m<2;m++)
    #pragma unroll
    for (int n=0;n<2;n++)
      #pragma unroll
      for (int t=0;t<4;t++) a2[m][n][t] = 0.f;
  const int swr = (lm & 7) << 3;
  for (int kf=0; kf<32; ++kf) {
    s16x8 af[2], bfr[2];
    #pragma unroll
    for (int m=0;m<2;m++)
      af[m] = *reinterpret_cast<const s16x8*>(&hls[(m*16+lm)*1024 + ((kf*32 + lg*8) ^ swr)]);
    #pragma unroll
    for (int n=0;n<2;n++)
      bfr[n] = *reinterpret_cast<const s16x8*>(&w2t[(size_t)(nc0+n*16+lm)*1024 + kf*32 + lg*8]);
    #pragma unroll
    for (int m=0;m<2;m++)
      #pragma unroll
      for (int n=0;n<2;n++)
        a2[m][n] = __builtin_amdgcn_mfma_f32_16x16x32_bf16(af[m], bfr[n], a2[m][n], 0, 0, 0);
  }

  // ---------------- epilogue: bias + residual + LN (8-wave reduction)
  float bb2[2];
  #pragma unroll
  for (int n=0;n<2;n++) bb2[n] = b2[nc0 + n*16 + lm];
  #pragma unroll
  for (int m=0;m<2;m++)
    #pragma unroll
    for (int j=0;j<4;j++){
      const int r = m*16 + lg*4 + j;
      const u16* resp = xbf + (size_t)(m0+r)*256 + nc0 + lm;
      #pragma unroll
      for (int n=0;n<2;n++) a2[m][n][j] += bb2[n] + b2f(resp[n*16]);
    }
  #pragma unroll
  for (int m=0;m<2;m++)
    #pragma unroll
    for (int j=0;j<4;j++){
      float s1 = 0.f, s2 = 0.f;
      #pragma unroll
      for (int n=0;n<2;n++){ const float t2 = a2[m][n][j]; s1 += t2; s2 += t2*t2; }
      s1 += __shfl_xor(s1, 1); s2 += __shfl_xor(s2, 1);
      s1 += __shfl_xor(s1, 2); s2 += __shfl_xor(s2, 2);
      s1 += __shfl_xor(s1, 4); s2 += __shfl_xor(s2, 4);
      s1 += __shfl_xor(s1, 8); s2 += __shfl_xor(s2, 8);
      if (lm == 0){ const int r = m*16 + lg*4 + j; redS[w][r] = s1; redQ[w][r] = s2; }
    }
  __syncthreads();

  float gg[2], be[2];
  #pragma unroll
  for (int n=0;n<2;n++){ const int col = nc0 + n*16 + lm; gg[n] = lng[col]; be[n] = lnb[col]; }
  #pragma unroll
  for (int m=0;m<2;m++)
    #pragma unroll
    for (int j=0;j<4;j++){
      const int r = m*16 + lg*4 + j;
      float sum = 0.f, sq = 0.f;
      #pragma unroll
      for (int u=0;u<8;u++){ sum += redS[u][r]; sq += redQ[u][r]; }
      const float mean = sum * (1.f/256.f);
      const float var  = sq  * (1.f/256.f) - mean*mean;
      const float rstd = rsqrtf(var + 1e-5f);
      #pragma unroll
      for (int n=0;n<2;n++){
        const float y = (a2[m][n][j] - mean)*rstd*gg[n] + be[n];
        // each wave reads+writes only its own 32-col slice; residual reads happened
        // pre-barrier, so no cross-wave hazard.
        const_cast<u16*>(xbf)[(size_t)(m0+r)*256 + nc0 + n*16 + lm] = f2b(y);
      }
    }
}

// ---------------------------------------------------------------- head (fp32, reads bf16 cls)
__global__ __launch_bounds__(256) void head_kernel(
    const u16* __restrict__ xbf,
    const float* __restrict__ projW, const float* __restrict__ projb,
    const float* __restrict__ W1, const float* __restrict__ b1,
    const float* __restrict__ W2, const float* __restrict__ b2,
    const float* __restrict__ W3, const float* __restrict__ b3,
    float* __restrict__ out)
{
  const int b = blockIdx.x, tid = threadIdx.x;
  __shared__ float c_s[256];
  __shared__ float h_s[256];
  __shared__ float red[3][4];
  const float c = b2f(xbf[((size_t)b*S_)*256 + tid]);
  c_s[tid] = c;
  __syncthreads();
  float a1 = b1[tid];
  #pragma unroll 8
  for (int k=0;k<256;k++) a1 += c_s[k]*W1[k*256+tid];
  a1 = fmaxf(a1, 0.f);
  h_s[tid] = a1;
  __syncthreads();
  float a2 = b2[tid];
  #pragma unroll 8
  for (int k=0;k<256;k++) a2 += h_s[k]*W2[k*256+tid];
  a2 = fmaxf(a2, 0.f);

  float pv = a2 * W3[tid];
  float p0 = c * projW[tid*2];
  float p1 = c * projW[tid*2+1];
  #pragma unroll
  for (int o=1;o<64;o<<=1){
    pv += __shfl_xor(pv, o);
    p0 += __shfl_xor(p0, o);
    p1 += __shfl_xor(p1, o);
  }
  const int w = tid >> 6;
  if ((tid & 63) == 0){ red[0][w]=p0; red[1][w]=p1; red[2][w]=pv; }
  __syncthreads();
  if (tid == 0){
    const float q0 = red[0][0]+red[0][1]+red[0][2]+red[0][3] + projb[0];
    const float q1 = red[1][0]+red[1][1]+red[1][2]+red[1][3] + projb[1];
    const float qv = red[2][0]+red[2][1]+red[2][2]+red[2][3] + b3[0];
    out[b*3+0] = tanhf(q0);
    out[b*3+1] = tanhf(q1);
    out[b*3+2] = qv;
  }
}

__global__ void fallback_ws(float* out, int n, float val){
  const int i = blockIdx.x*256 + threadIdx.x;
  if (i < n) out[i] = val;
}

// ---------------------------------------------------------------- launch
extern "C" void kernel_launch(void* const* d_in, const int* in_sizes, int n_in,
                              void* d_out, int out_size, void* d_ws, size_t ws_size,
                              hipStream_t stream)
{
  (void)in_sizes; (void)n_in;
  const float* obs      = (const float*)d_in[0];
  const float* cls_emb  = (const float*)d_in[1];
  const float* type_cls = (const float*)d_in[2];
  const float* type_ctx = (const float*)d_in[3];
  const float* type_pred= (const float*)d_in[4];
  const float* type_boid= (const float*)d_in[5];
  const float* ctx_W    = (const float*)d_in[6];
  const float* ctx_b    = (const float*)d_in[7];
  const float* pred_W   = (const float*)d_in[8];
  const float* pred_b   = (const float*)d_in[9];
  const float* boid_W   = (const float*)d_in[10];
  const float* boid_b   = (const float*)d_in[11];
  const float* qkv_W    = (const float*)d_in[12];
  const float* qkv_b    = (const float*)d_in[13];
  const float* out_W    = (const float*)d_in[14];
  const float* out_b    = (const float*)d_in[15];
  const float* ln1_g    = (const float*)d_in[16];
  const float* ln1_b    = (const float*)d_in[17];
  const float* ffn_W1   = (const float*)d_in[18];
  const float* ffn_b1   = (const float*)d_in[19];
  const float* ffn_W2   = (const float*)d_in[20];
  const float* ffn_b2   = (const float*)d_in[21];
  const float* ln2_g    = (const float*)d_in[22];
  const float* ln2_b    = (const float*)d_in[23];
  const float* proj_W   = (const float*)d_in[24];
  const float* proj_b   = (const float*)d_in[25];
  const float* vh_W1    = (const float*)d_in[26];
  const float* vh_b1    = (const float*)d_in[27];
  const float* vh_W2    = (const float*)d_in[28];
  const float* vh_b2    = (const float*)d_in[29];
  const float* vh_W3    = (const float*)d_in[30];
  const float* vh_b3    = (const float*)d_in[31];

  const size_t SZ_WQ = (size_t)L_*768*256*2;
  const size_t SZ_WO = (size_t)L_*256*256*2;
  const size_t SZ_W1 = (size_t)L_*1024*256*2;
  const size_t SZ_W2 = (size_t)L_*256*1024*2;
  const size_t SZ_W  = SZ_WQ + SZ_WO + SZ_W1 + SZ_W2;  // 9437184

  // per-B bytes: xbf 512 + big 2048 (qkv 1536 | obuf 512) per row, ×53 + 4 = 135684
  size_t avail = (ws_size > SZ_W + 8192) ? (ws_size - SZ_W - 8192) : 0;
  long long bcm = (long long)(avail / 135684ull);
  if (bcm > B_) bcm = B_;
  int Bc_max = (int)((bcm / 128) * 128);
  if (Bc_max < 128) {
    const float val = 2000.0f + (float)(ws_size >> 20);
    fallback_ws<<<(out_size+255)/256, 256, 0, stream>>>((float*)d_out, out_size, val);
    return;
  }
  const size_t Mc_max = (size_t)Bc_max * S_;

  char* ws = (char*)d_ws;
  u16* wq  = (u16*)(ws);
  u16* wo  = (u16*)(ws + SZ_WQ);
  u16* w1t = (u16*)(ws + SZ_WQ + SZ_WO);
  u16* w2t = (u16*)(ws + SZ_WQ + SZ_WO + SZ_W1);
  char* act = ws + SZ_W;
  u16* xbf  = (u16*)(act);
  u16* big  = (u16*)(act + Mc_max*512);
  u16* obuf = big + Mc_max*768;
  int* nval = (int*)(act + Mc_max*512 + Mc_max*2048);

  prep_weights<<<6144, 256, 0, stream>>>(qkv_W, out_W, ffn_W1, ffn_W2, wq, wo, w1t, w2t);

  int b0 = 0;
  while (b0 < B_) {
    const int Bc = (B_ - b0 < Bc_max) ? (B_ - b0) : Bc_max;
    const int Mc = Bc * S_;
    embed_kernel<<<Bc, 256, 0, stream>>>(obs + (size_t)b0*204,
        cls_emb, type_cls, type_ctx, type_pred, type_boid,
        ctx_W, ctx_b, pred_W, pred_b, boid_W, boid_b,
        xbf, nval);
    for (int l = 0; l < L_; ++l) {
      gemm_bias_kernel<false><<<dim3(Mc/128, 6), 256, 0, stream>>>(
          xbf, wq + (size_t)l*768*256, qkv_b + l*768, big, 768, 256);
      attn_kernel<<<Bc*H_, 64, 0, stream>>>(big, obuf, nval);
      gemm_ln_kernel<<<Mc/64, 256, 0, stream>>>(
          obuf, wo + (size_t)l*256*256, out_b + l*256, ln1_g + l*256, ln1_b + l*256,
          xbf, 256);
      ffn2_kernel<<<Mc/32, 512, 0, stream>>>(
          xbf,
          w1t + (size_t)l*1024*256, ffn_b1 + l*1024,
          w2t + (size_t)l*256*1024, ffn_b2 + l*256,
          ln2_g + l*256, ln2_b + l*256);
    }
    head_kernel<<<Bc, 256, 0, stream>>>(xbf, proj_W, proj_b, vh_W1, vh_b1, vh_W2, vh_b2,
                                        vh_W3, vh_b3, (float*)d_out + (size_t)b0*3);
    b0 += Bc;
  }
}

// Round 12
// 5161.436 us; speedup vs baseline: 1.7335x; 1.7335x over previous
//
#include <hip/hip_runtime.h>
#include <hip/hip_bf16.h>
#include <stdint.h>

typedef unsigned short u16;
typedef short s16x8 __attribute__((ext_vector_type(8)));
typedef float f32x4 __attribute__((ext_vector_type(4)));

#define D_ 256
#define H_ 8
#define L_ 6
#define F_ 1024
#define MAXB_ 50
#define S_ 53
#define B_ 4096

__device__ __forceinline__ u16 f2b(float f){
  __hip_bfloat16 h = __float2bfloat16(f);   // RNE
  return *reinterpret_cast<u16*>(&h);
}
__device__ __forceinline__ float b2f(u16 u){
  __hip_bfloat16 h = *reinterpret_cast<__hip_bfloat16*>(&u);
  return __bfloat162float(h);
}

__device__ __forceinline__ void gload16(const void* g, void* l){
  __builtin_amdgcn_global_load_lds((__attribute__((address_space(1))) void*)(g),
                                   (__attribute__((address_space(3))) void*)(l), 16, 0, 0);
}

// ---------------------------------------------------------------- weights prep
__global__ __launch_bounds__(256) void prep_weights(
    const float* __restrict__ qkvW, const float* __restrict__ outW,
    const float* __restrict__ w1,   const float* __restrict__ w2,
    u16* __restrict__ qkvT, u16* __restrict__ outT,
    u16* __restrict__ w1T,  u16* __restrict__ w2T)
{
  const int i = blockIdx.x * 256 + threadIdx.x;
  if (i < L_*768*256) {            // qkvT[l][n<768][k<256]
    const int l = i / (768*256); const int r = i % (768*256);
    const int n = r >> 8; const int k = r & 255;
    qkvT[i] = f2b(qkvW[((size_t)l*256 + k)*768 + n]);
  }
  if (i < L_*256*256) {            // outT[l][n<256][k<256]
    const int l = i >> 16; const int r = i & 65535;
    const int n = r >> 8; const int k = r & 255;
    outT[i] = f2b(outW[((size_t)l*256 + k)*256 + n]);
  }
  if (i < L_*1024*256) {           // w1T[l][n<1024][k<256]
    const int l = i / (1024*256); const int r = i % (1024*256);
    const int n = r >> 8; const int k = r & 255;
    w1T[i] = f2b(w1[((size_t)l*256 + k)*1024 + n]);
  }
  if (i < L_*256*1024) {           // w2T[l][n<256][k<1024]
    const int l = i / (256*1024); const int r = i % (256*1024);
    const int n = r >> 10; const int k = r & 1023;
    w2T[i] = f2b(w2[((size_t)l*1024 + k)*256 + n]);
  }
}

// ---------------------------------------------------------------- embedding (per chunk)
__global__ __launch_bounds__(256) void embed_kernel(
    const float* __restrict__ obs,
    const float* __restrict__ cls_emb, const float* __restrict__ type_cls,
    const float* __restrict__ type_ctx, const float* __restrict__ type_pred,
    const float* __restrict__ type_boid,
    const float* __restrict__ ctxW, const float* __restrict__ ctxb,
    const float* __restrict__ predW, const float* __restrict__ predb,
    const float* __restrict__ boidW, const float* __restrict__ boidb,
    u16* __restrict__ xbf, int* __restrict__ nvalid)
{
  const int b = blockIdx.x, tid = threadIdx.x;
  __shared__ float obs_s[204];
  __shared__ int perm_s[MAXB_];
  __shared__ int count_s;
  const float* orow = obs + (size_t)b * 204;
  if (tid < 204) obs_s[tid] = orow[tid];
  __syncthreads();
  if (tid < 64) {
    const int j = tid;
    bool flag = false;
    if (j < MAXB_) {
      const float a0=obs_s[4+4*j], a1=obs_s[5+4*j], a2=obs_s[6+4*j], a3=obs_s[7+4*j];
      flag = (a0!=0.f)||(a1!=0.f)||(a2!=0.f)||(a3!=0.f);
    }
    const unsigned long long m = __ballot(flag);
    if (flag) perm_s[__popcll(m & ((1ull<<j)-1ull))] = j;
    if (j == 0) { count_s = __popcll(m); nvalid[b] = __popcll(m); }
  }
  __syncthreads();
  const int cnt = count_s;
  const int d = tid;
  for (int s = 0; s < S_; ++s) {
    float v;
    if (s == 0)      v = cls_emb[d] + type_cls[d];
    else if (s == 1) v = obs_s[0]*ctxW[d] + obs_s[1]*ctxW[256+d] + ctxb[d] + type_ctx[d];
    else if (s == 2) v = obs_s[2]*predW[d] + obs_s[3]*predW[256+d] + predb[d] + type_pred[d];
    else {
      const int j = s - 3;
      if (j < cnt) {
        const int bj = perm_s[j];
        v = obs_s[4+4*bj]*boidW[d] + obs_s[5+4*bj]*boidW[256+d]
          + obs_s[6+4*bj]*boidW[512+d] + obs_s[7+4*bj]*boidW[768+d]
          + boidb[d] + type_boid[d];
      } else v = 0.f;
    }
    xbf[((size_t)b*S_ + s)*256 + d] = f2b(v);
  }
}

// ---------------------------------------------------------------- GEMM + bias (+relu)
// R5-proven: 128x128 tile, BK=64, 4 waves, dbuf prefetch-before-compute, T2 swizzle.
// NEW: 1-D grid, N-major linearization + bijective chunked XCD swizzle (T1/m204):
// each XCD executes a contiguous run of lids; consecutive lids share the A-panel.
template<bool RELU>
__global__ __launch_bounds__(256, 2) void gemm_bias_kernel(
    const u16* __restrict__ A, const u16* __restrict__ Bt,
    const float* __restrict__ bias, u16* __restrict__ C,
    int N, int K, int NBN)   // NBN = N/128
{
  const int nwg = gridDim.x;
  const int q = nwg >> 3, r = nwg & 7;
  const int xcd = blockIdx.x & 7, off = blockIdx.x >> 3;
  const int lid = (xcd < r ? xcd*(q+1) : r*(q+1) + (xcd - r)*q) + off;
  const int m0 = (lid / NBN) * 128, n0 = (lid % NBN) * 128;

  __shared__ __attribute__((aligned(16))) u16 As[2][128*64];
  __shared__ __attribute__((aligned(16))) u16 Bs[2][128*64];
  const int tid = threadIdx.x;
  const int w = tid >> 6, lane = tid & 63;
  const int wr = w >> 1, wc = w & 1;
  const int lm = lane & 15, lg = lane >> 4;
  const int lrow = lane >> 3;
  const int lxor = ((lane & 7) ^ lrow) * 8;
  const int cb0 = (lg*16) ^ ((lm & 7) << 4);
  const int cb1 = (64 + lg*16) ^ ((lm & 7) << 4);

  f32x4 acc[4][4];
  #pragma unroll
  for (int m=0;m<4;m++)
    #pragma unroll
    for (int n=0;n<4;n++)
      #pragma unroll
      for (int t=0;t<4;t++) acc[m][n][t] = 0.f;

  #pragma unroll
  for (int j=0;j<4;j++){
    const int chunk = w*4 + j;
    const int row = chunk*8 + lrow;
    gload16(A  + (size_t)(m0+row)*K + lxor, &As[0][chunk*512]);
    gload16(Bt + (size_t)(n0+row)*K + lxor, &Bs[0][chunk*512]);
  }
  __syncthreads();

  const int NT = K >> 6;
  for (int t = 0; t < NT; ++t) {
    const int cur = t & 1;
    if (t + 1 < NT) {
      const int k0 = (t+1) << 6;
      #pragma unroll
      for (int j=0;j<4;j++){
        const int chunk = w*4 + j;
        const int row = chunk*8 + lrow;
        gload16(A  + (size_t)(m0+row)*K + k0 + lxor, &As[cur^1][chunk*512]);
        gload16(Bt + (size_t)(n0+row)*K + k0 + lxor, &Bs[cur^1][chunk*512]);
      }
    }
    const char* Ab = (const char*)As[cur];
    const char* Bb = (const char*)Bs[cur];
    #pragma unroll
    for (int kk=0;kk<2;kk++){
      const int cb = kk ? cb1 : cb0;
      s16x8 af[4], bfr[4];
      #pragma unroll
      for (int m=0;m<4;m++) af[m]  = *reinterpret_cast<const s16x8*>(Ab + (wr*64 + m*16 + lm)*128 + cb);
      #pragma unroll
      for (int n=0;n<4;n++) bfr[n] = *reinterpret_cast<const s16x8*>(Bb + (wc*64 + n*16 + lm)*128 + cb);
      #pragma unroll
      for (int m=0;m<4;m++)
        #pragma unroll
        for (int n=0;n<4;n++)
          acc[m][n] = __builtin_amdgcn_mfma_f32_16x16x32_bf16(af[m], bfr[n], acc[m][n], 0, 0, 0);
    }
    __syncthreads();
  }

  #pragma unroll
  for (int n=0;n<4;n++){
    const int col = n0 + wc*64 + n*16 + lm;
    const float bv = bias[col];
    #pragma unroll
    for (int m=0;m<4;m++){
      const int r0 = m0 + wr*64 + m*16 + lg*4;
      #pragma unroll
      for (int j=0;j<4;j++){
        float v = acc[m][n][j] + bv;
        if (RELU) v = fmaxf(v, 0.f);
        C[(size_t)(r0+j)*N + col] = f2b(v);
      }
    }
  }
}

// ---------------------------------------------------------------- attention
__global__ __launch_bounds__(64) void attn_kernel(
    const u16* __restrict__ qkv, u16* __restrict__ O, const int* __restrict__ nvalid)
{
  const int bh = blockIdx.x;
  const int b = bh >> 3, h = bh & 7;
  const int lane = threadIdx.x;
  const int lm = lane & 15, lg = lane >> 4;
  __shared__ __attribute__((aligned(16))) u16 Pl[64*72];
  __shared__ __attribute__((aligned(16))) u16 VT[32*72];
  const size_t base = (size_t)b * S_ * 768;

  s16x8 aQ[4], aK[4];
  #pragma unroll
  for (int t=0;t<4;t++){
    const int r = t*16 + lm;
    if (r < S_){
      aQ[t] = *reinterpret_cast<const s16x8*>(&qkv[base + (size_t)r*768 +       h*32 + lg*8]);
      aK[t] = *reinterpret_cast<const s16x8*>(&qkv[base + (size_t)r*768 + 256 + h*32 + lg*8]);
    } else {
      #pragma unroll
      for (int i=0;i<8;i++){ aQ[t][i]=0; aK[t][i]=0; }
    }
  }
  {
    const int s = lane;
    #pragma unroll
    for (int i4=0;i4<4;i4++){
      s16x8 v;
      if (s < S_) v = *reinterpret_cast<const s16x8*>(&qkv[base + (size_t)s*768 + 512 + h*32 + i4*8]);
      else {
        #pragma unroll
        for (int i=0;i<8;i++) v[i]=0;
      }
      #pragma unroll
      for (int t=0;t<8;t++) VT[(i4*8+t)*72 + s] = (u16)v[t];
    }
  }
  f32x4 zf;
  #pragma unroll
  for (int t=0;t<4;t++) zf[t] = 0.f;
  f32x4 sc[4][4];
  #pragma unroll
  for (int qi=0;qi<4;qi++)
    #pragma unroll
    for (int kj=0;kj<4;kj++)
      sc[qi][kj] = __builtin_amdgcn_mfma_f32_16x16x32_bf16(aQ[qi], aK[kj], zf, 0, 0, 0);

  const int T = 3 + nvalid[b];
  const float scale = 0.17677669529663689f;
  __syncthreads();

  #pragma unroll
  for (int qi=0;qi<4;qi++){
    #pragma unroll
    for (int j=0;j<4;j++){
      float v[4];
      #pragma unroll
      for (int kj=0;kj<4;kj++)
        v[kj] = sc[qi][kj][j]*scale + ((kj*16+lm) < T ? 0.f : -1e9f);
      float mx = fmaxf(fmaxf(v[0],v[1]), fmaxf(v[2],v[3]));
      mx = fmaxf(mx, __shfl_xor(mx, 1));
      mx = fmaxf(mx, __shfl_xor(mx, 2));
      mx = fmaxf(mx, __shfl_xor(mx, 4));
      mx = fmaxf(mx, __shfl_xor(mx, 8));
      float e[4]; float sum = 0.f;
      #pragma unroll
      for (int kj=0;kj<4;kj++){ e[kj] = __expf(v[kj]-mx); sum += e[kj]; }
      sum += __shfl_xor(sum, 1);
      sum += __shfl_xor(sum, 2);
      sum += __shfl_xor(sum, 4);
      sum += __shfl_xor(sum, 8);
      const float inv = 1.f / sum;
      const int q = qi*16 + lg*4 + j;
      #pragma unroll
      for (int kj=0;kj<4;kj++) Pl[q*72 + kj*16 + lm] = f2b(e[kj]*inv);
    }
  }
  __syncthreads();

  s16x8 bV[2][2];
  #pragma unroll
  for (int c=0;c<2;c++)
    #pragma unroll
    for (int dj=0;dj<2;dj++)
      bV[c][dj] = *reinterpret_cast<const s16x8*>(&VT[(dj*16+lm)*72 + c*32 + lg*8]);

  f32x4 oa[4][2];
  #pragma unroll
  for (int qi=0;qi<4;qi++)
    #pragma unroll
    for (int dj=0;dj<2;dj++)
      #pragma unroll
      for (int t=0;t<4;t++) oa[qi][dj][t] = 0.f;

  #pragma unroll
  for (int qi=0;qi<4;qi++){
    #pragma unroll
    for (int c=0;c<2;c++){
      const s16x8 aP = *reinterpret_cast<const s16x8*>(&Pl[(qi*16+lm)*72 + c*32 + lg*8]);
      #pragma unroll
      for (int dj=0;dj<2;dj++)
        oa[qi][dj] = __builtin_amdgcn_mfma_f32_16x16x32_bf16(aP, bV[c][dj], oa[qi][dj], 0, 0, 0);
    }
  }
  #pragma unroll
  for (int qi=0;qi<4;qi++)
    #pragma unroll
    for (int dj=0;dj<2;dj++)
      #pragma unroll
      for (int j=0;j<4;j++){
        const int q = qi*16 + lg*4 + j;
        if (q < S_)
          O[((size_t)(b*S_ + q))*256 + h*32 + dj*16 + lm] = f2b(oa[qi][dj][j]);
      }
}

// ---------------------------------------------------------------- GEMM + bias + residual + LayerNorm
// R5-proven: 128 rows x 256 cols per block; 8 waves (2 wr x 4 wc), each wave 64x64.
// Double-buffered BK=64 with prefetch-before-compute; T2 swizzle both sides.
__global__ __launch_bounds__(512, 2) void gemm_ln_kernel(
    const u16* __restrict__ A, const u16* __restrict__ Bt,
    const float* __restrict__ bias, const float* __restrict__ lng, const float* __restrict__ lnb,
    u16* __restrict__ xbf, int K)
{
  __shared__ __attribute__((aligned(16))) u16 As[2][128*64];
  __shared__ __attribute__((aligned(16))) u16 Bs[2][256*64];
  __shared__ float redS[4][128];
  __shared__ float redQ[4][128];
  const int tid = threadIdx.x;
  const int w = tid >> 6, lane = tid & 63;
  const int wr = w >> 2, wc = w & 3;
  const int lm = lane & 15, lg = lane >> 4;
  const int lrow = lane >> 3;
  const int lxor = ((lane & 7) ^ lrow) * 8;
  const int m0 = blockIdx.x * 128;
  const int cb0 = (lg*16) ^ ((lm & 7) << 4);
  const int cb1 = (64 + lg*16) ^ ((lm & 7) << 4);

  f32x4 acc[4][4];
  #pragma unroll
  for (int m=0;m<4;m++)
    #pragma unroll
    for (int n=0;n<4;n++)
      #pragma unroll
      for (int t=0;t<4;t++) acc[m][n][t] = 0.f;

  #pragma unroll
  for (int j=0;j<2;j++){
    const int chunk = w*2 + j;
    gload16(A + (size_t)(m0 + chunk*8 + lrow)*K + lxor, &As[0][chunk*512]);
  }
  #pragma unroll
  for (int j=0;j<4;j++){
    const int chunk = w*4 + j;
    gload16(Bt + (size_t)(chunk*8 + lrow)*K + lxor, &Bs[0][chunk*512]);
  }
  __syncthreads();

  const int NT = K >> 6;
  for (int t = 0; t < NT; ++t) {
    const int cur = t & 1;
    if (t + 1 < NT) {
      const int k0 = (t+1) << 6;
      #pragma unroll
      for (int j=0;j<2;j++){
        const int chunk = w*2 + j;
        gload16(A + (size_t)(m0 + chunk*8 + lrow)*K + k0 + lxor, &As[cur^1][chunk*512]);
      }
      #pragma unroll
      for (int j=0;j<4;j++){
        const int chunk = w*4 + j;
        gload16(Bt + (size_t)(chunk*8 + lrow)*K + k0 + lxor, &Bs[cur^1][chunk*512]);
      }
    }
    const char* Ab = (const char*)As[cur];
    const char* Bb = (const char*)Bs[cur];
    #pragma unroll
    for (int kk=0;kk<2;kk++){
      const int cb = kk ? cb1 : cb0;
      s16x8 af[4], bfr[4];
      #pragma unroll
      for (int m=0;m<4;m++) af[m]  = *reinterpret_cast<const s16x8*>(Ab + (wr*64 + m*16 + lm)*128 + cb);
      #pragma unroll
      for (int n=0;n<4;n++) bfr[n] = *reinterpret_cast<const s16x8*>(Bb + (wc*64 + n*16 + lm)*128 + cb);
      #pragma unroll
      for (int m=0;m<4;m++)
        #pragma unroll
        for (int n=0;n<4;n++)
          acc[m][n] = __builtin_amdgcn_mfma_f32_16x16x32_bf16(af[m], bfr[n], acc[m][n], 0, 0, 0);
    }
    __syncthreads();
  }

  // bias + residual (residual from bf16 x)
  float bb[4];
  #pragma unroll
  for (int n=0;n<4;n++) bb[n] = bias[wc*64 + n*16 + lm];
  #pragma unroll
  for (int m=0;m<4;m++)
    #pragma unroll
    for (int j=0;j<4;j++){
      const int r = wr*64 + m*16 + lg*4 + j;
      const u16* resp = xbf + (size_t)(m0+r)*256 + wc*64 + lm;
      #pragma unroll
      for (int n=0;n<4;n++) acc[m][n][j] += bb[n] + b2f(resp[n*16]);
    }

  #pragma unroll
  for (int m=0;m<4;m++)
    #pragma unroll
    for (int j=0;j<4;j++){
      float s1 = 0.f, s2 = 0.f;
      #pragma unroll
      for (int n=0;n<4;n++){ const float t2 = acc[m][n][j]; s1 += t2; s2 += t2*t2; }
      s1 += __shfl_xor(s1, 1); s2 += __shfl_xor(s2, 1);
      s1 += __shfl_xor(s1, 2); s2 += __shfl_xor(s2, 2);
      s1 += __shfl_xor(s1, 4); s2 += __shfl_xor(s2, 4);
      s1 += __shfl_xor(s1, 8); s2 += __shfl_xor(s2, 8);
      if (lm == 0){ const int r = wr*64 + m*16 + lg*4 + j; redS[wc][r] = s1; redQ[wc][r] = s2; }
    }
  __syncthreads();

  float gg[4], be[4];
  #pragma unroll
  for (int n=0;n<4;n++){ const int col = wc*64 + n*16 + lm; gg[n] = lng[col]; be[n] = lnb[col]; }
  #pragma unroll
  for (int m=0;m<4;m++)
    #pragma unroll
    for (int j=0;j<4;j++){
      const int r = wr*64 + m*16 + lg*4 + j;
      const float sum = redS[0][r]+redS[1][r]+redS[2][r]+redS[3][r];
      const float sq  = redQ[0][r]+redQ[1][r]+redQ[2][r]+redQ[3][r];
      const float mean = sum * (1.f/256.f);
      const float var  = sq  * (1.f/256.f) - mean*mean;
      const float rstd = rsqrtf(var + 1e-5f);
      #pragma unroll
      for (int n=0;n<4;n++){
        const float y = (acc[m][n][j] - mean)*rstd*gg[n] + be[n];
        xbf[(size_t)(m0+r)*256 + wc*64 + n*16 + lm] = f2b(y);
      }
    }
}

// ---------------------------------------------------------------- head (fp32, reads bf16 cls)
__global__ __launch_bounds__(256) void head_kernel(
    const u16* __restrict__ xbf,
    const float* __restrict__ projW, const float* __restrict__ projb,
    const float* __restrict__ W1, const float* __restrict__ b1,
    const float* __restrict__ W2, const float* __restrict__ b2,
    const float* __restrict__ W3, const float* __restrict__ b3,
    float* __restrict__ out)
{
  const int b = blockIdx.x, tid = threadIdx.x;
  __shared__ float c_s[256];
  __shared__ float h_s[256];
  __shared__ float red[3][4];
  const float c = b2f(xbf[((size_t)b*S_)*256 + tid]);
  c_s[tid] = c;
  __syncthreads();
  float a1 = b1[tid];
  #pragma unroll 8
  for (int k=0;k<256;k++) a1 += c_s[k]*W1[k*256+tid];
  a1 = fmaxf(a1, 0.f);
  h_s[tid] = a1;
  __syncthreads();
  float a2 = b2[tid];
  #pragma unroll 8
  for (int k=0;k<256;k++) a2 += h_s[k]*W2[k*256+tid];
  a2 = fmaxf(a2, 0.f);

  float pv = a2 * W3[tid];
  float p0 = c * projW[tid*2];
  float p1 = c * projW[tid*2+1];
  #pragma unroll
  for (int o=1;o<64;o<<=1){
    pv += __shfl_xor(pv, o);
    p0 += __shfl_xor(p0, o);
    p1 += __shfl_xor(p1, o);
  }
  const int w = tid >> 6;
  if ((tid & 63) == 0){ red[0][w]=p0; red[1][w]=p1; red[2][w]=pv; }
  __syncthreads();
  if (tid == 0){
    const float q0 = red[0][0]+red[0][1]+red[0][2]+red[0][3] + projb[0];
    const float q1 = red[1][0]+red[1][1]+red[1][2]+red[1][3] + projb[1];
    const float qv = red[2][0]+red[2][1]+red[2][2]+red[2][3] + b3[0];
    out[b*3+0] = tanhf(q0);
    out[b*3+1] = tanhf(q1);
    out[b*3+2] = qv;
  }
}

__global__ void fallback_ws(float* out, int n, float val){
  const int i = blockIdx.x*256 + threadIdx.x;
  if (i < n) out[i] = val;
}

// ---------------------------------------------------------------- launch
extern "C" void kernel_launch(void* const* d_in, const int* in_sizes, int n_in,
                              void* d_out, int out_size, void* d_ws, size_t ws_size,
                              hipStream_t stream)
{
  (void)in_sizes; (void)n_in;
  const float* obs      = (const float*)d_in[0];
  const float* cls_emb  = (const float*)d_in[1];
  const float* type_cls = (const float*)d_in[2];
  const float* type_ctx = (const float*)d_in[3];
  const float* type_pred= (const float*)d_in[4];
  const float* type_boid= (const float*)d_in[5];
  const float* ctx_W    = (const float*)d_in[6];
  const float* ctx_b    = (const float*)d_in[7];
  const float* pred_W   = (const float*)d_in[8];
  const float* pred_b   = (const float*)d_in[9];
  const float* boid_W   = (const float*)d_in[10];
  const float* boid_b   = (const float*)d_in[11];
  const float* qkv_W    = (const float*)d_in[12];
  const float* qkv_b    = (const float*)d_in[13];
  const float* out_W    = (const float*)d_in[14];
  const float* out_b    = (const float*)d_in[15];
  const float* ln1_g    = (const float*)d_in[16];
  const float* ln1_b    = (const float*)d_in[17];
  const float* ffn_W1   = (const float*)d_in[18];
  const float* ffn_b1   = (const float*)d_in[19];
  const float* ffn_W2   = (const float*)d_in[20];
  const float* ffn_b2   = (const float*)d_in[21];
  const float* ln2_g    = (const float*)d_in[22];
  const float* ln2_b    = (const float*)d_in[23];
  const float* proj_W   = (const float*)d_in[24];
  const float* proj_b   = (const float*)d_in[25];
  const float* vh_W1    = (const float*)d_in[26];
  const float* vh_b1    = (const float*)d_in[27];
  const float* vh_W2    = (const float*)d_in[28];
  const float* vh_b2    = (const float*)d_in[29];
  const float* vh_W3    = (const float*)d_in[30];
  const float* vh_b3    = (const float*)d_in[31];

  // --- weights region (bf16, transposed) ---
  const size_t SZ_WQ = (size_t)L_*768*256*2;   // 2359296
  const size_t SZ_WO = (size_t)L_*256*256*2;   //  786432
  const size_t SZ_W1 = (size_t)L_*1024*256*2;  // 3145728
  const size_t SZ_W2 = (size_t)L_*256*1024*2;  // 3145728
  const size_t SZ_W  = SZ_WQ + SZ_WO + SZ_W1 + SZ_W2;  // 9437184

  // per-element act bytes: xbf 512 + big 2048 (qkv 1536 | obuf overlay 512 | h 2048) = 2560
  // per B: 135684 ; Bc multiple of 128 (M/128 tiles)
  size_t avail = (ws_size > SZ_W + 8192) ? (ws_size - SZ_W - 8192) : 0;
  long long bcm = (long long)(avail / 135684ull);
  if (bcm > B_) bcm = B_;
  int Bc_max = (int)((bcm / 128) * 128);
  if (Bc_max < 128) {
    const float val = 2000.0f + (float)(ws_size >> 20);
    fallback_ws<<<(out_size+255)/256, 256, 0, stream>>>((float*)d_out, out_size, val);
    return;
  }
  const size_t Mc_max = (size_t)Bc_max * S_;

  char* ws = (char*)d_ws;
  u16* wq  = (u16*)(ws);
  u16* wo  = (u16*)(ws + SZ_WQ);
  u16* w1t = (u16*)(ws + SZ_WQ + SZ_WO);
  u16* w2t = (u16*)(ws + SZ_WQ + SZ_WO + SZ_W1);
  char* act = ws + SZ_W;
  u16* xbf  = (u16*)(act);
  u16* big  = (u16*)(act + Mc_max*512);               // qkv (1536B/row) / h (2048B/row)
  u16* obuf = big + Mc_max*768;                       // overlay in big's tail 512B/row
  int* nval = (int*)(act + Mc_max*512 + Mc_max*2048);

  prep_weights<<<6144, 256, 0, stream>>>(qkv_W, out_W, ffn_W1, ffn_W2, wq, wo, w1t, w2t);

  int b0 = 0;
  while (b0 < B_) {
    const int Bc = (B_ - b0 < Bc_max) ? (B_ - b0) : Bc_max;   // multiples of 128
    const int Mc = Bc * S_;
    embed_kernel<<<Bc, 256, 0, stream>>>(obs + (size_t)b0*204,
        cls_emb, type_cls, type_ctx, type_pred, type_boid,
        ctx_W, ctx_b, pred_W, pred_b, boid_W, boid_b,
        xbf, nval);
    for (int l = 0; l < L_; ++l) {
      gemm_bias_kernel<false><<<(Mc/128)*6, 256, 0, stream>>>(
          xbf, wq + (size_t)l*768*256, qkv_b + l*768, big, 768, 256, 6);
      attn_kernel<<<Bc*H_, 64, 0, stream>>>(big, obuf, nval);
      gemm_ln_kernel<<<Mc/128, 512, 0, stream>>>(
          obuf, wo + (size_t)l*256*256, out_b + l*256, ln1_g + l*256, ln1_b + l*256,
          xbf, 256);
      gemm_bias_kernel<true><<<(Mc/128)*8, 256, 0, stream>>>(
          xbf, w1t + (size_t)l*1024*256, ffn_b1 + l*1024, big, 1024, 256, 8);
      gemm_ln_kernel<<<Mc/128, 512, 0, stream>>>(
          big, w2t + (size_t)l*256*1024, ffn_b2 + l*256, ln2_g + l*256, ln2_b + l*256,
          xbf, 1024);
    }
    head_kernel<<<Bc, 256, 0, stream>>>(xbf, proj_W, proj_b, vh_W1, vh_b1, vh_W2, vh_b2,
                                        vh_W3, vh_b3, (float*)d_out + (size_t)b0*3);
    b0 += Bc;
  }
}